// Round 9
// baseline (38.951 us; speedup 1.0000x reference)
//
#include <hip/hip_runtime.h>

// FFT convolution via N = 2^18 = 64 x 4096 Cooley-Tukey, 3 dispatches.
//   n = 4096*n1 + n2, k = k1 + 64*k2.
// ka   : distributed 64-pt column FFT over n1 (+ W_N^{-n2 k1}) -> A1[seq][k1][n2]
//        (8 thr/column; blocks 0..7 also fill the W4096 table)
// kmid2: 192 blocks x 512. Blocks 0..63 (producers, launched first): fwd 4096-FFT
//        of rir row k1 -> SpecR[k1] + release flag. Blocks 64..191 (consumers):
//        fwd 4096-FFT of z row (spectrum stays in REGISTERS), acquire flag[k1],
//        read SpecR row, pointwise*1/N, inverse FFT, +W_N^{+n2 k1} -> D[z][k1][n2].
//        All 192 blocks co-resident (<=256 CUs) => no deadlock. One-shot acquire,
//        not a grid barrier (R6 lesson: repeated agent barriers thrash L2 -> 75us).
// kc   : distributed 64-pt inverse column FFT over k1, unpack -> out.

#define NTOT 262144
#define TLEN 131072
#define PI2_N     2.3968449808418217e-5f   /* 2*pi / 262144 */
#define PI2_32768 1.9174759848570515e-4f   /* 2*pi / 32768  */
#define PI2_4096  1.5339807878856412e-3f   /* 2*pi / 4096   */
#define PI2_512   1.2271846303085129e-2f   /* 2*pi / 512    */
#define PI2_64    9.8174770424681039e-2f   /* 2*pi / 64     */
#define LB(i) ((i) + ((i) >> 3))           /* LDS pad */

__device__ __forceinline__ float2 cadd(float2 a, float2 b) { return make_float2(a.x + b.x, a.y + b.y); }
__device__ __forceinline__ float2 csub(float2 a, float2 b) { return make_float2(a.x - b.x, a.y - b.y); }
__device__ __forceinline__ float2 cmul(float2 a, float2 b) {
    return make_float2(a.x * b.x - a.y * b.y, a.x * b.y + a.y * b.x);
}
__device__ __forceinline__ float2 cmulc(float2 a, float2 b) {   // a * conj(b)
    return make_float2(a.x * b.x + a.y * b.y, a.y * b.x - a.x * b.y);
}
__device__ __forceinline__ float2 cexp_(float ang) {
    float s, c;
    __sincosf(ang, &s, &c);
    return make_float2(c, s);
}

template<int SIGN>
__device__ __forceinline__ void dft8(float2 x[8]) {
    const float R2 = 0.70710678118654752f;
    float2 t0 = cadd(x[0], x[4]), t1 = csub(x[0], x[4]);
    float2 t2 = cadd(x[2], x[6]), t3 = csub(x[2], x[6]);
    float2 u0 = cadd(x[1], x[5]), u1 = csub(x[1], x[5]);
    float2 u2 = cadd(x[3], x[7]), u3 = csub(x[3], x[7]);
    float2 it3 = (SIGN > 0) ? make_float2(-t3.y, t3.x) : make_float2(t3.y, -t3.x);
    float2 iu3 = (SIGN > 0) ? make_float2(-u3.y, u3.x) : make_float2(u3.y, -u3.x);
    float2 E0 = cadd(t0, t2), E2 = csub(t0, t2);
    float2 E1 = cadd(t1, it3), E3 = csub(t1, it3);
    float2 O0 = cadd(u0, u2), O2 = csub(u0, u2);
    float2 O1 = cadd(u1, iu3), O3 = csub(u1, iu3);
    float2 iO2 = (SIGN > 0) ? make_float2(-O2.y, O2.x) : make_float2(O2.y, -O2.x);
    float2 w1O1 = (SIGN > 0) ? make_float2(R2 * (O1.x - O1.y), R2 * (O1.y + O1.x))
                             : make_float2(R2 * (O1.x + O1.y), R2 * (O1.y - O1.x));
    float2 w3O3 = (SIGN > 0) ? make_float2(R2 * (-O3.x - O3.y), R2 * (O3.x - O3.y))
                             : make_float2(R2 * (O3.y - O3.x), R2 * (-O3.x - O3.y));
    x[0] = cadd(E0, O0);   x[4] = csub(E0, O0);
    x[1] = cadd(E1, w1O1); x[5] = csub(E1, w1O1);
    x[2] = cadd(E2, iO2);  x[6] = csub(E2, iO2);
    x[3] = cadd(E3, w3O3); x[7] = csub(E3, w3O3);
}

// dft8 with x[4..7] == 0 structurally (reads only x[0..3])
template<int SIGN>
__device__ __forceinline__ void dft8z(float2 x[8]) {
    const float R2 = 0.70710678118654752f;
    float2 x0 = x[0], x1 = x[1], x2 = x[2], x3 = x[3];
    float2 rx2 = (SIGN > 0) ? make_float2(-x2.y, x2.x) : make_float2(x2.y, -x2.x);
    float2 rx3 = (SIGN > 0) ? make_float2(-x3.y, x3.x) : make_float2(x3.y, -x3.x);
    float2 E0 = cadd(x0, x2), E2 = csub(x0, x2);
    float2 E1 = cadd(x0, rx2), E3 = csub(x0, rx2);
    float2 O0 = cadd(x1, x3), O2 = csub(x1, x3);
    float2 O1 = cadd(x1, rx3), O3 = csub(x1, rx3);
    float2 iO2 = (SIGN > 0) ? make_float2(-O2.y, O2.x) : make_float2(O2.y, -O2.x);
    float2 w1O1 = (SIGN > 0) ? make_float2(R2 * (O1.x - O1.y), R2 * (O1.y + O1.x))
                             : make_float2(R2 * (O1.x + O1.y), R2 * (O1.y - O1.x));
    float2 w3O3 = (SIGN > 0) ? make_float2(R2 * (-O3.x - O3.y), R2 * (O3.x - O3.y))
                             : make_float2(R2 * (O3.y - O3.x), R2 * (-O3.x - O3.y));
    x[0] = cadd(E0, O0);   x[4] = csub(E0, O0);
    x[1] = cadd(E1, w1O1); x[5] = csub(E1, w1O1);
    x[2] = cadd(E2, iO2);  x[6] = csub(E2, iO2);
    x[3] = cadd(E3, w3O3); x[7] = csub(E3, w3O3);
}

// twiddle by W4096^(base*i) from table (tab[j] = e^{-2pi i j/4096}); conj for inverse.
template<int SIGN>
__device__ __forceinline__ void twtab(float2 x[8], int base, const float2* __restrict__ tab) {
#pragma unroll
    for (int i = 1; i < 8; ++i) {
        float2 w = tab[base * i];
        x[i] = (SIGN < 0) ? cmul(x[i], w) : cmulc(x[i], w);
    }
}

// 4096-pt radix-8 Stockham FFT, t in [0,512), double-buffered LDS L0/L1.
// Leading __syncthreads covers WAR vs the caller's previous use of L0/L1.
template<int SIGN>
__device__ void fft4096(float2 x[8], int t, float2* L0, float2* L1,
                        const float2* __restrict__ tab) {
    __syncthreads();
    dft8<SIGN>(x);
    twtab<SIGN>(x, t, tab);
#pragma unroll
    for (int i = 0; i < 8; ++i) L0[LB(8 * t + i)] = x[i];
    __syncthreads();
    {
        int q = t & 7, p = t >> 3;
#pragma unroll
        for (int i = 0; i < 8; ++i) x[i] = L0[LB(q + 8 * p + 512 * i)];
        dft8<SIGN>(x);
        twtab<SIGN>(x, 8 * p, tab);
#pragma unroll
        for (int i = 0; i < 8; ++i) L1[LB(q + 64 * p + 8 * i)] = x[i];
    }
    __syncthreads();
    {
        int q = t & 63, p = t >> 6;
#pragma unroll
        for (int i = 0; i < 8; ++i) x[i] = L1[LB(q + 64 * p + 512 * i)];
        dft8<SIGN>(x);
        twtab<SIGN>(x, 64 * p, tab);
#pragma unroll
        for (int i = 0; i < 8; ++i) L0[LB(q + 512 * p + 64 * i)] = x[i];
    }
    __syncthreads();
#pragma unroll
    for (int i = 0; i < 8; ++i) x[i] = L0[LB(t + 512 * i)];
    dft8<SIGN>(x);
}

// ka: 192 blocks x 512. Distributed 64-pt column FFT (8 thr/col, 64 cols/block).
__global__ void __launch_bounds__(512) ka(const float* __restrict__ audio,
                                          const float* __restrict__ rir,
                                          float2* __restrict__ A1,
                                          float2* __restrict__ tab) {
    __shared__ float2 Lsh[64 * 73];
    const int bid = blockIdx.x;
    const int tid = threadIdx.x;
    const int t = tid & 7;
    const int c = tid >> 3;

    if (bid < 8)                          // fill W4096 table (read by kmid2/kc next)
        tab[bid * 512 + tid] = cexp_(-PI2_4096 * (float)(bid * 512 + tid));

    int seq = bid >> 6;
    int n2 = ((bid & 63) << 6) + c;
    float2 g[8];
    if (seq < 2) {
        const float* c0 = audio + (size_t)(2 * seq) * TLEN;
        const float* c1 = c0 + TLEN;
#pragma unroll
        for (int i = 0; i < 4; ++i) {
            int n = ((t + 8 * i) << 12) + n2;          // n1 = t+8i < 32 (nonzero half)
            g[i] = make_float2(c0[n], c1[n]);
        }
    } else {
#pragma unroll
        for (int i = 0; i < 4; ++i) {
            int n = ((t + 8 * i) << 12) + n2;
            g[i] = make_float2(rir[TLEN - 1 - n], 0.f);
        }
    }
    dft8z<-1>(g);
#pragma unroll
    for (int i = 1; i < 8; ++i)
        g[i] = cmul(g[i], cexp_(-PI2_64 * (float)(t * i)));
    float2* col = Lsh + (size_t)c * 73;
#pragma unroll
    for (int i = 0; i < 8; ++i) col[t + 8 * i] = g[i];
    __syncthreads();
#pragma unroll
    for (int i = 0; i < 8; ++i) g[i] = col[8 * t + i];
    dft8<-1>(g);
    // W_N^{-n2*(8i+t)} = W_N^{-n2 t} * (W_N^{-8 n2})^i
    float2 w  = cexp_(-PI2_N * (float)(n2 * t));
    float2 st = cexp_(-PI2_32768 * (float)n2);
    float2* dst = A1 + ((size_t)seq << 18) + n2;
#pragma unroll
    for (int i = 0; i < 8; ++i) {
        dst[(size_t)(8 * i + t) << 12] = cmul(g[i], w);   // k1 = rev8(8t+i) = 8i+t
        w = cmul(w, st);
    }
}

// kmid2: 192 blocks x 512. Producers (0..63): rir rows. Consumers (64..191): z rows.
__global__ void __launch_bounds__(512) kmid2(const float2* __restrict__ A1,
                                             float2* __restrict__ SpecR,
                                             float2* __restrict__ D,
                                             const float2* __restrict__ tab,
                                             unsigned* __restrict__ flags) {
    __shared__ float2 L0[4608], L1[4608];
    const int t = threadIdx.x;
    const int bid = blockIdx.x;

    if (bid < 64) {
        // ---- producer: forward FFT of rir row k1 = bid ----
        const float2* src = A1 + ((size_t)(128 + bid) << 12);
        float2 x[8];
#pragma unroll
        for (int i = 0; i < 8; ++i) x[i] = src[t + 512 * i];
        fft4096<-1>(x, t, L0, L1, tab);
        float2* dst = SpecR + ((size_t)bid << 12) + t;
#pragma unroll
        for (int i = 0; i < 8; ++i) dst[512 * i] = x[i];
        // each wave's stores drained by the vmcnt(0) before s_barrier; then release.
        __syncthreads();
        if (t == 0)
            __hip_atomic_store(&flags[bid], 1u, __ATOMIC_RELEASE, __HIP_MEMORY_SCOPE_AGENT);
    } else {
        // ---- consumer: z row (row = bid-64), spectrum kept in registers ----
        const int row = bid - 64;          // 0..127 (z*64 + k1)
        const int k1 = row & 63;
        const float2* src = A1 + ((size_t)row << 12);
        float2 x[8];
#pragma unroll
        for (int i = 0; i < 8; ++i) x[i] = src[t + 512 * i];
        fft4096<-1>(x, t, L0, L1, tab);

        // one-shot acquire of the rir spectrum row
        if (t == 0) {
            while (!__hip_atomic_load(&flags[k1], __ATOMIC_ACQUIRE, __HIP_MEMORY_SCOPE_AGENT))
                __builtin_amdgcn_s_sleep(2);
        }
        __syncthreads();

        const float2* sr = SpecR + ((size_t)k1 << 12);
        float2 r8[8];
#pragma unroll
        for (int i = 0; i < 8; ++i) r8[i] = sr[t + 512 * i];

        const float invN = 3.814697265625e-6f;   // 1/262144
#pragma unroll
        for (int i = 0; i < 8; ++i) {
            float2 y = cmul(x[i], r8[i]);
            x[i] = make_float2(y.x * invN, y.y * invN);
        }

        fft4096<1>(x, t, L0, L1, tab);

        // W_N^{+n2 k1}, n2 = t+512i: chain from W_N^{t k1}, step W_512^{k1}
        float2 w  = cexp_(PI2_N * (float)(t * k1));
        float2 st = cexp_(PI2_512 * (float)k1);
        float2* d = D + ((size_t)row << 12) + t;
#pragma unroll
        for (int i = 0; i < 8; ++i) {
            d[512 * i] = cmul(x[i], w);
            w = cmul(w, st);
        }
    }
}

// kc: 128 blocks x 512. Distributed 64-pt inverse column FFT over k1 + unpack.
__global__ void __launch_bounds__(512) kc(const float2* __restrict__ D,
                                          float* __restrict__ out, int Lout,
                                          const float2* __restrict__ tab) {
    __shared__ float2 Lsh[64 * 73];
    const int bid = blockIdx.x;
    const int tid = threadIdx.x;
    const int t = tid & 7;
    const int c = tid >> 3;
    int z = bid >> 6;
    int n2 = ((bid & 63) << 6) + c;

    const float2* src = D + ((size_t)z << 18) + n2;
    float2 g[8];
#pragma unroll
    for (int i = 0; i < 8; ++i)
        g[i] = src[(size_t)(8 * i + t) << 12];          // input[k1=8i+t] -> phys x[8t+i]
    dft8<1>(g);
#pragma unroll
    for (int i = 1; i < 8; ++i)
        g[i] = cmulc(g[i], tab[64 * t * i]);            // W64^{+ti} = conj(tab[64 t i])
    float2* col = Lsh + (size_t)c * 73;
#pragma unroll
    for (int i = 0; i < 8; ++i) col[8 * t + i] = g[i];
    __syncthreads();
#pragma unroll
    for (int i = 0; i < 8; ++i) g[i] = col[t + 8 * i];
    dft8<1>(g);
    float* o0 = out + (size_t)(2 * z) * Lout;
    float* o1 = o0 + Lout;
#pragma unroll
    for (int i = 0; i < 8; ++i) {
        int n = ((t + 8 * i) << 12) + n2;               // n1 = t+8i natural
        if (n < Lout) { o0[n] = g[i].x; o1[n] = g[i].y; }
    }
}

extern "C" void kernel_launch(void* const* d_in, const int* in_sizes, int n_in,
                              void* d_out, int out_size, void* d_ws, size_t ws_size,
                              hipStream_t stream) {
    const float* audio = (const float*)d_in[0];   // (1, 4, T) f32
    const float* rir   = (const float*)d_in[1];   // (T,) f32
    float* out = (float*)d_out;                   // (1, 4, 2T-1) f32
    int Lout = out_size / 4;                      // 262143

    float2* A1    = (float2*)d_ws;                // 3 * 2^18 complex  (6.3 MB)
    float2* D     = A1 + 3 * NTOT;                // 2 * 2^18 complex  (4.2 MB)
    float2* SpecR = D + 2 * NTOT;                 // 64 * 4096 complex (2.1 MB)
    float2* tab   = SpecR + 64 * 4096;            // 4096 complex (32 KB)
    unsigned* flags = (unsigned*)(tab + 4096);    // 64 u32

    hipMemsetAsync(flags, 0, 64 * sizeof(unsigned), stream);   // re-arm handshake每 call
    ka   <<<192, 512, 0, stream>>>(audio, rir, A1, tab);
    kmid2<<<192, 512, 0, stream>>>(A1, SpecR, D, tab, flags);
    kc   <<<128, 512, 0, stream>>>(D, out, Lout, tab);
}

// Round 10
// 35.657 us; speedup vs baseline: 1.0924x; 1.0924x over previous
//
#include <hip/hip_runtime.h>

// FFT convolution via N = 2^18 = 64 x 4096 Cooley-Tukey, 3 dispatches.
//   n = 4096*n1 + n2, k = k1 + 64*k2.
// ka   : distributed 64-pt column FFT over n1 (+ W_N^{-n2 k1}) -> A1[seq][k1][n2]
// kmid3: 192 blocks x 512. Blocks 0..63 (producers): fwd 4096-FFT of rir row k1,
//        write SpecR[k1] with SYSTEM-COHERENT (sc0 sc1) stores + flag release.
//        Blocks 64..191 (consumers): fwd 4096-FFT of z row (spectrum in REGISTERS),
//        spin on flag (sc load), read SpecR with sc loads (bypass L1/L2 -> no
//        cache-wide invalidate, unlike R6/R9's agent atomics), pointwise*1/N,
//        inverse FFT, +W_N^{+n2 k1} -> D[z][k1][n2].
//        192 blocks co-resident on 256 CUs => no deadlock window.
// kc   : distributed 64-pt inverse column FFT over k1, unpack -> out.

#define NTOT 262144
#define TLEN 131072
#define PI2_N     2.3968449808418217e-5f   /* 2*pi / 262144 */
#define PI2_32768 1.9174759848570515e-4f   /* 2*pi / 32768  */
#define PI2_4096  1.5339807878856412e-3f   /* 2*pi / 4096   */
#define PI2_512   1.2271846303085129e-2f   /* 2*pi / 512    */
#define PI2_64    9.8174770424681039e-2f   /* 2*pi / 64     */
#define LB(i) ((i) + ((i) >> 3))           /* LDS pad */

typedef float fv2 __attribute__((ext_vector_type(2)));

__device__ __forceinline__ float2 cadd(float2 a, float2 b) { return make_float2(a.x + b.x, a.y + b.y); }
__device__ __forceinline__ float2 csub(float2 a, float2 b) { return make_float2(a.x - b.x, a.y - b.y); }
__device__ __forceinline__ float2 cmul(float2 a, float2 b) {
    return make_float2(a.x * b.x - a.y * b.y, a.x * b.y + a.y * b.x);
}
__device__ __forceinline__ float2 cmulc(float2 a, float2 b) {   // a * conj(b)
    return make_float2(a.x * b.x + a.y * b.y, a.y * b.x - a.x * b.y);
}
__device__ __forceinline__ float2 cexp_(float ang) {
    float s, c;
    __sincosf(ang, &s, &c);
    return make_float2(c, s);
}

template<int SIGN>
__device__ __forceinline__ void dft8(float2 x[8]) {
    const float R2 = 0.70710678118654752f;
    float2 t0 = cadd(x[0], x[4]), t1 = csub(x[0], x[4]);
    float2 t2 = cadd(x[2], x[6]), t3 = csub(x[2], x[6]);
    float2 u0 = cadd(x[1], x[5]), u1 = csub(x[1], x[5]);
    float2 u2 = cadd(x[3], x[7]), u3 = csub(x[3], x[7]);
    float2 it3 = (SIGN > 0) ? make_float2(-t3.y, t3.x) : make_float2(t3.y, -t3.x);
    float2 iu3 = (SIGN > 0) ? make_float2(-u3.y, u3.x) : make_float2(u3.y, -u3.x);
    float2 E0 = cadd(t0, t2), E2 = csub(t0, t2);
    float2 E1 = cadd(t1, it3), E3 = csub(t1, it3);
    float2 O0 = cadd(u0, u2), O2 = csub(u0, u2);
    float2 O1 = cadd(u1, iu3), O3 = csub(u1, iu3);
    float2 iO2 = (SIGN > 0) ? make_float2(-O2.y, O2.x) : make_float2(O2.y, -O2.x);
    float2 w1O1 = (SIGN > 0) ? make_float2(R2 * (O1.x - O1.y), R2 * (O1.y + O1.x))
                             : make_float2(R2 * (O1.x + O1.y), R2 * (O1.y - O1.x));
    float2 w3O3 = (SIGN > 0) ? make_float2(R2 * (-O3.x - O3.y), R2 * (O3.x - O3.y))
                             : make_float2(R2 * (O3.y - O3.x), R2 * (-O3.x - O3.y));
    x[0] = cadd(E0, O0);   x[4] = csub(E0, O0);
    x[1] = cadd(E1, w1O1); x[5] = csub(E1, w1O1);
    x[2] = cadd(E2, iO2);  x[6] = csub(E2, iO2);
    x[3] = cadd(E3, w3O3); x[7] = csub(E3, w3O3);
}

// dft8 with x[4..7] == 0 structurally (reads only x[0..3])
template<int SIGN>
__device__ __forceinline__ void dft8z(float2 x[8]) {
    const float R2 = 0.70710678118654752f;
    float2 x0 = x[0], x1 = x[1], x2 = x[2], x3 = x[3];
    float2 rx2 = (SIGN > 0) ? make_float2(-x2.y, x2.x) : make_float2(x2.y, -x2.x);
    float2 rx3 = (SIGN > 0) ? make_float2(-x3.y, x3.x) : make_float2(x3.y, -x3.x);
    float2 E0 = cadd(x0, x2), E2 = csub(x0, x2);
    float2 E1 = cadd(x0, rx2), E3 = csub(x0, rx2);
    float2 O0 = cadd(x1, x3), O2 = csub(x1, x3);
    float2 O1 = cadd(x1, rx3), O3 = csub(x1, rx3);
    float2 iO2 = (SIGN > 0) ? make_float2(-O2.y, O2.x) : make_float2(O2.y, -O2.x);
    float2 w1O1 = (SIGN > 0) ? make_float2(R2 * (O1.x - O1.y), R2 * (O1.y + O1.x))
                             : make_float2(R2 * (O1.x + O1.y), R2 * (O1.y - O1.x));
    float2 w3O3 = (SIGN > 0) ? make_float2(R2 * (-O3.x - O3.y), R2 * (O3.x - O3.y))
                             : make_float2(R2 * (O3.y - O3.x), R2 * (-O3.x - O3.y));
    x[0] = cadd(E0, O0);   x[4] = csub(E0, O0);
    x[1] = cadd(E1, w1O1); x[5] = csub(E1, w1O1);
    x[2] = cadd(E2, iO2);  x[6] = csub(E2, iO2);
    x[3] = cadd(E3, w3O3); x[7] = csub(E3, w3O3);
}

template<int SIGN>
__device__ __forceinline__ void twtab(float2 x[8], int base, const float2* __restrict__ tab) {
#pragma unroll
    for (int i = 1; i < 8; ++i) {
        float2 w = tab[base * i];
        x[i] = (SIGN < 0) ? cmul(x[i], w) : cmulc(x[i], w);
    }
}

// 4096-pt radix-8 Stockham FFT, t in [0,512), double-buffered LDS L0/L1.
template<int SIGN>
__device__ void fft4096(float2 x[8], int t, float2* L0, float2* L1,
                        const float2* __restrict__ tab) {
    __syncthreads();
    dft8<SIGN>(x);
    twtab<SIGN>(x, t, tab);
#pragma unroll
    for (int i = 0; i < 8; ++i) L0[LB(8 * t + i)] = x[i];
    __syncthreads();
    {
        int q = t & 7, p = t >> 3;
#pragma unroll
        for (int i = 0; i < 8; ++i) x[i] = L0[LB(q + 8 * p + 512 * i)];
        dft8<SIGN>(x);
        twtab<SIGN>(x, 8 * p, tab);
#pragma unroll
        for (int i = 0; i < 8; ++i) L1[LB(q + 64 * p + 8 * i)] = x[i];
    }
    __syncthreads();
    {
        int q = t & 63, p = t >> 6;
#pragma unroll
        for (int i = 0; i < 8; ++i) x[i] = L1[LB(q + 64 * p + 512 * i)];
        dft8<SIGN>(x);
        twtab<SIGN>(x, 64 * p, tab);
#pragma unroll
        for (int i = 0; i < 8; ++i) L0[LB(q + 512 * p + 64 * i)] = x[i];
    }
    __syncthreads();
#pragma unroll
    for (int i = 0; i < 8; ++i) x[i] = L0[LB(t + 512 * i)];
    dft8<SIGN>(x);
}

// ---- system-coherent (sc0 sc1) access helpers: bypass L1/L2, no cache invalidate ----
__device__ __forceinline__ fv2 tofv(float2 a) { fv2 r; r[0] = a.x; r[1] = a.y; return r; }

__device__ __forceinline__ void st_sys_row(float2* base, int t, const float2 x[8]) {
    fv2 v0 = tofv(x[0]), v1 = tofv(x[1]), v2 = tofv(x[2]), v3 = tofv(x[3]);
    fv2 v4 = tofv(x[4]), v5 = tofv(x[5]), v6 = tofv(x[6]), v7 = tofv(x[7]);
    const float2 *p0 = base + t,        *p1 = base + t + 512,  *p2 = base + t + 1024,
                 *p3 = base + t + 1536, *p4 = base + t + 2048, *p5 = base + t + 2560,
                 *p6 = base + t + 3072, *p7 = base + t + 3584;
    asm volatile(
        "global_store_dwordx2 %8, %0, off sc0 sc1\n\t"
        "global_store_dwordx2 %9, %1, off sc0 sc1\n\t"
        "global_store_dwordx2 %10, %2, off sc0 sc1\n\t"
        "global_store_dwordx2 %11, %3, off sc0 sc1\n\t"
        "global_store_dwordx2 %12, %4, off sc0 sc1\n\t"
        "global_store_dwordx2 %13, %5, off sc0 sc1\n\t"
        "global_store_dwordx2 %14, %6, off sc0 sc1\n\t"
        "global_store_dwordx2 %15, %7, off sc0 sc1\n\t"
        "s_waitcnt vmcnt(0)"
        :: "v"(v0), "v"(v1), "v"(v2), "v"(v3), "v"(v4), "v"(v5), "v"(v6), "v"(v7),
           "v"(p0), "v"(p1), "v"(p2), "v"(p3), "v"(p4), "v"(p5), "v"(p6), "v"(p7)
        : "memory");
}

__device__ __forceinline__ void ld_sys_row(const float2* base, int t, float2 r[8]) {
    fv2 a0, a1, a2, a3, a4, a5, a6, a7;
    const float2 *p0 = base + t,        *p1 = base + t + 512,  *p2 = base + t + 1024,
                 *p3 = base + t + 1536, *p4 = base + t + 2048, *p5 = base + t + 2560,
                 *p6 = base + t + 3072, *p7 = base + t + 3584;
    asm volatile(
        "global_load_dwordx2 %0, %8, off sc0 sc1\n\t"
        "global_load_dwordx2 %1, %9, off sc0 sc1\n\t"
        "global_load_dwordx2 %2, %10, off sc0 sc1\n\t"
        "global_load_dwordx2 %3, %11, off sc0 sc1\n\t"
        "global_load_dwordx2 %4, %12, off sc0 sc1\n\t"
        "global_load_dwordx2 %5, %13, off sc0 sc1\n\t"
        "global_load_dwordx2 %6, %14, off sc0 sc1\n\t"
        "global_load_dwordx2 %7, %15, off sc0 sc1\n\t"
        "s_waitcnt vmcnt(0)"
        : "=&v"(a0), "=&v"(a1), "=&v"(a2), "=&v"(a3),
          "=&v"(a4), "=&v"(a5), "=&v"(a6), "=&v"(a7)
        : "v"(p0), "v"(p1), "v"(p2), "v"(p3), "v"(p4), "v"(p5), "v"(p6), "v"(p7)
        : "memory");
    r[0] = make_float2(a0[0], a0[1]); r[1] = make_float2(a1[0], a1[1]);
    r[2] = make_float2(a2[0], a2[1]); r[3] = make_float2(a3[0], a3[1]);
    r[4] = make_float2(a4[0], a4[1]); r[5] = make_float2(a5[0], a5[1]);
    r[6] = make_float2(a6[0], a6[1]); r[7] = make_float2(a7[0], a7[1]);
}

// ka: 192 blocks x 512. Distributed 64-pt column FFT (8 thr/col, 64 cols/block).
__global__ void __launch_bounds__(512) ka(const float* __restrict__ audio,
                                          const float* __restrict__ rir,
                                          float2* __restrict__ A1,
                                          float2* __restrict__ tab) {
    __shared__ float2 Lsh[64 * 73];
    const int bid = blockIdx.x;
    const int tid = threadIdx.x;
    const int t = tid & 7;
    const int c = tid >> 3;

    if (bid < 8)                          // fill W4096 table (read by kmid3/kc next)
        tab[bid * 512 + tid] = cexp_(-PI2_4096 * (float)(bid * 512 + tid));

    int seq = bid >> 6;
    int n2 = ((bid & 63) << 6) + c;
    float2 g[8];
    if (seq < 2) {
        const float* c0 = audio + (size_t)(2 * seq) * TLEN;
        const float* c1 = c0 + TLEN;
#pragma unroll
        for (int i = 0; i < 4; ++i) {
            int n = ((t + 8 * i) << 12) + n2;          // n1 = t+8i < 32 (nonzero half)
            g[i] = make_float2(c0[n], c1[n]);
        }
    } else {
#pragma unroll
        for (int i = 0; i < 4; ++i) {
            int n = ((t + 8 * i) << 12) + n2;
            g[i] = make_float2(rir[TLEN - 1 - n], 0.f);
        }
    }
    dft8z<-1>(g);
#pragma unroll
    for (int i = 1; i < 8; ++i)
        g[i] = cmul(g[i], cexp_(-PI2_64 * (float)(t * i)));
    float2* col = Lsh + (size_t)c * 73;
#pragma unroll
    for (int i = 0; i < 8; ++i) col[t + 8 * i] = g[i];
    __syncthreads();
#pragma unroll
    for (int i = 0; i < 8; ++i) g[i] = col[8 * t + i];
    dft8<-1>(g);
    // W_N^{-n2*(8i+t)} = W_N^{-n2 t} * (W_N^{-8 n2})^i
    float2 w  = cexp_(-PI2_N * (float)(n2 * t));
    float2 st = cexp_(-PI2_32768 * (float)n2);
    float2* dst = A1 + ((size_t)seq << 18) + n2;
#pragma unroll
    for (int i = 0; i < 8; ++i) {
        dst[(size_t)(8 * i + t) << 12] = cmul(g[i], w);   // k1 = rev8(8t+i) = 8i+t
        w = cmul(w, st);
    }
}

// kmid3: 192 blocks x 512. Producers (0..63): rir rows -> SpecR (sc stores) + flag.
// Consumers (64..191): z rows, spectrum in regs; sc-load SpecR; pointwise; inverse.
__global__ void __launch_bounds__(512) kmid3(const float2* __restrict__ A1,
                                             float2* __restrict__ SpecR,
                                             float2* __restrict__ D,
                                             const float2* __restrict__ tab,
                                             unsigned* __restrict__ flags) {
    __shared__ float2 L0[4608], L1[4608];
    const int t = threadIdx.x;
    const int bid = blockIdx.x;

    if (bid < 64) {
        // ---- producer: forward FFT of rir row k1 = bid ----
        const float2* src = A1 + ((size_t)(128 + bid) << 12);
        float2 x[8];
#pragma unroll
        for (int i = 0; i < 8; ++i) x[i] = src[t + 512 * i];
        fft4096<-1>(x, t, L0, L1, tab);
        st_sys_row(SpecR + ((size_t)bid << 12), t, x);   // write-through + vmcnt(0)
        __syncthreads();                                  // all threads' stores done
        if (t == 0) {
            unsigned one = 1;
            const unsigned* fp = &flags[bid];
            asm volatile("global_store_dword %0, %1, off sc0 sc1"
                         :: "v"(fp), "v"(one) : "memory");
        }
    } else {
        // ---- consumer: z row (row = bid-64), spectrum kept in registers ----
        const int row = bid - 64;          // 0..127 (z*64 + k1)
        const int k1 = row & 63;
        const float2* src = A1 + ((size_t)row << 12);
        float2 x[8];
#pragma unroll
        for (int i = 0; i < 8; ++i) x[i] = src[t + 512 * i];
        fft4096<-1>(x, t, L0, L1, tab);

        // one-shot acquire: spin on flag with system-scope loads (no cache inv)
        if (t == 0) {
            const unsigned* fp = &flags[k1];
            unsigned v;
            do {
                asm volatile("global_load_dword %0, %1, off sc0 sc1\n\t"
                             "s_waitcnt vmcnt(0)"
                             : "=v"(v) : "v"(fp) : "memory");
                if (v) break;
                asm volatile("s_sleep 8");
            } while (1);
        }
        __syncthreads();

        float2 r8[8];
        ld_sys_row(SpecR + ((size_t)k1 << 12), t, r8);   // bypass L1/L2 -> fresh from L3

        const float invN = 3.814697265625e-6f;   // 1/262144
#pragma unroll
        for (int i = 0; i < 8; ++i) {
            float2 y = cmul(x[i], r8[i]);
            x[i] = make_float2(y.x * invN, y.y * invN);
        }

        fft4096<1>(x, t, L0, L1, tab);

        // W_N^{+n2 k1}, n2 = t+512i: chain from W_N^{t k1}, step W_512^{k1}
        float2 w  = cexp_(PI2_N * (float)(t * k1));
        float2 st = cexp_(PI2_512 * (float)k1);
        float2* d = D + ((size_t)row << 12) + t;
#pragma unroll
        for (int i = 0; i < 8; ++i) {
            d[512 * i] = cmul(x[i], w);
            w = cmul(w, st);
        }
    }
}

// kc: 128 blocks x 512. Distributed 64-pt inverse column FFT over k1 + unpack.
__global__ void __launch_bounds__(512) kc(const float2* __restrict__ D,
                                          float* __restrict__ out, int Lout,
                                          const float2* __restrict__ tab) {
    __shared__ float2 Lsh[64 * 73];
    const int bid = blockIdx.x;
    const int tid = threadIdx.x;
    const int t = tid & 7;
    const int c = tid >> 3;
    int z = bid >> 6;
    int n2 = ((bid & 63) << 6) + c;

    const float2* src = D + ((size_t)z << 18) + n2;
    float2 g[8];
#pragma unroll
    for (int i = 0; i < 8; ++i)
        g[i] = src[(size_t)(8 * i + t) << 12];          // input[k1=8i+t] -> phys x[8t+i]
    dft8<1>(g);
#pragma unroll
    for (int i = 1; i < 8; ++i)
        g[i] = cmulc(g[i], tab[64 * t * i]);            // W64^{+ti} = conj(tab[64 t i])
    float2* col = Lsh + (size_t)c * 73;
#pragma unroll
    for (int i = 0; i < 8; ++i) col[8 * t + i] = g[i];
    __syncthreads();
#pragma unroll
    for (int i = 0; i < 8; ++i) g[i] = col[t + 8 * i];
    dft8<1>(g);
    float* o0 = out + (size_t)(2 * z) * Lout;
    float* o1 = o0 + Lout;
#pragma unroll
    for (int i = 0; i < 8; ++i) {
        int n = ((t + 8 * i) << 12) + n2;               // n1 = t+8i natural
        if (n < Lout) { o0[n] = g[i].x; o1[n] = g[i].y; }
    }
}

extern "C" void kernel_launch(void* const* d_in, const int* in_sizes, int n_in,
                              void* d_out, int out_size, void* d_ws, size_t ws_size,
                              hipStream_t stream) {
    const float* audio = (const float*)d_in[0];   // (1, 4, T) f32
    const float* rir   = (const float*)d_in[1];   // (T,) f32
    float* out = (float*)d_out;                   // (1, 4, 2T-1) f32
    int Lout = out_size / 4;                      // 262143

    float2* A1    = (float2*)d_ws;                // 3 * 2^18 complex  (6.3 MB)
    float2* D     = A1 + 3 * NTOT;                // 2 * 2^18 complex  (4.2 MB)
    float2* SpecR = D + 2 * NTOT;                 // 64 * 4096 complex (2.1 MB)
    float2* tab   = SpecR + 64 * 4096;            // 4096 complex (32 KB)
    unsigned* flags = (unsigned*)(tab + 4096);    // 64 u32

    hipMemsetAsync(flags, 0, 64 * sizeof(unsigned), stream);   // re-arm handshake
    ka   <<<192, 512, 0, stream>>>(audio, rir, A1, tab);
    kmid3<<<192, 512, 0, stream>>>(A1, SpecR, D, tab, flags);
    kc   <<<128, 512, 0, stream>>>(D, out, Lout, tab);
}

// Round 11
// 25.528 us; speedup vs baseline: 1.5258x; 1.3968x over previous
//
#include <hip/hip_runtime.h>

// FFT convolution via N = 2^18 = 64 x 4096 Cooley-Tukey, 4 dispatches (R7 structure).
//   n = 4096*n1 + n2, k = k1 + 64*k2.
// ka : distributed 64-pt column FFT over n1 (+ W_N^{-n2 k1})   -> A1[seq][k1][n2]
//      t = tid>>6 (wave-uniform radix slot), c = tid&63 -> all global I/O coalesced
//      256-512B per wave-instr; LDS exchange [j][c] lane-consecutive (conflict-free).
// kbf: forward 4096-pt row FFT per (seq,k1), table twiddles     -> Spec[seq][k1][k2]
// kbi: pointwise * 1/N + inverse 4096-pt row FFT (+W_N^{+n2 k1}) -> D[z][k1][n2]
// kc : distributed 64-pt inverse column FFT over k1, unpack.    -> out
// Lessons kept: no grid barriers / agent atomics / sc-bypass handshakes (R6/R9/R10:
// all cross-block sync variants cost 4-45us more than a dispatch boundary).

#define NTOT 262144
#define TLEN 131072
#define PI2_N     2.3968449808418217e-5f   /* 2*pi / 262144 */
#define PI2_32768 1.9174759848570515e-4f   /* 2*pi / 32768  */
#define PI2_4096  1.5339807878856412e-3f   /* 2*pi / 4096   */
#define PI2_512   1.2271846303085129e-2f   /* 2*pi / 512    */
#define PI2_64    9.8174770424681039e-2f   /* 2*pi / 64     */
#define LB(i) ((i) + ((i) >> 3))           /* LDS pad for row-FFT buffers */

__device__ __forceinline__ float2 cadd(float2 a, float2 b) { return make_float2(a.x + b.x, a.y + b.y); }
__device__ __forceinline__ float2 csub(float2 a, float2 b) { return make_float2(a.x - b.x, a.y - b.y); }
__device__ __forceinline__ float2 cmul(float2 a, float2 b) {
    return make_float2(a.x * b.x - a.y * b.y, a.x * b.y + a.y * b.x);
}
__device__ __forceinline__ float2 cmulc(float2 a, float2 b) {   // a * conj(b)
    return make_float2(a.x * b.x + a.y * b.y, a.y * b.x - a.x * b.y);
}
__device__ __forceinline__ float2 cexp_(float ang) {
    float s, c;
    __sincosf(ang, &s, &c);
    return make_float2(c, s);
}

template<int SIGN>
__device__ __forceinline__ void dft8(float2 x[8]) {
    const float R2 = 0.70710678118654752f;
    float2 t0 = cadd(x[0], x[4]), t1 = csub(x[0], x[4]);
    float2 t2 = cadd(x[2], x[6]), t3 = csub(x[2], x[6]);
    float2 u0 = cadd(x[1], x[5]), u1 = csub(x[1], x[5]);
    float2 u2 = cadd(x[3], x[7]), u3 = csub(x[3], x[7]);
    float2 it3 = (SIGN > 0) ? make_float2(-t3.y, t3.x) : make_float2(t3.y, -t3.x);
    float2 iu3 = (SIGN > 0) ? make_float2(-u3.y, u3.x) : make_float2(u3.y, -u3.x);
    float2 E0 = cadd(t0, t2), E2 = csub(t0, t2);
    float2 E1 = cadd(t1, it3), E3 = csub(t1, it3);
    float2 O0 = cadd(u0, u2), O2 = csub(u0, u2);
    float2 O1 = cadd(u1, iu3), O3 = csub(u1, iu3);
    float2 iO2 = (SIGN > 0) ? make_float2(-O2.y, O2.x) : make_float2(O2.y, -O2.x);
    float2 w1O1 = (SIGN > 0) ? make_float2(R2 * (O1.x - O1.y), R2 * (O1.y + O1.x))
                             : make_float2(R2 * (O1.x + O1.y), R2 * (O1.y - O1.x));
    float2 w3O3 = (SIGN > 0) ? make_float2(R2 * (-O3.x - O3.y), R2 * (O3.x - O3.y))
                             : make_float2(R2 * (O3.y - O3.x), R2 * (-O3.x - O3.y));
    x[0] = cadd(E0, O0);   x[4] = csub(E0, O0);
    x[1] = cadd(E1, w1O1); x[5] = csub(E1, w1O1);
    x[2] = cadd(E2, iO2);  x[6] = csub(E2, iO2);
    x[3] = cadd(E3, w3O3); x[7] = csub(E3, w3O3);
}

// dft8 with x[4..7] == 0 structurally (reads only x[0..3])
template<int SIGN>
__device__ __forceinline__ void dft8z(float2 x[8]) {
    const float R2 = 0.70710678118654752f;
    float2 x0 = x[0], x1 = x[1], x2 = x[2], x3 = x[3];
    float2 rx2 = (SIGN > 0) ? make_float2(-x2.y, x2.x) : make_float2(x2.y, -x2.x);
    float2 rx3 = (SIGN > 0) ? make_float2(-x3.y, x3.x) : make_float2(x3.y, -x3.x);
    float2 E0 = cadd(x0, x2), E2 = csub(x0, x2);
    float2 E1 = cadd(x0, rx2), E3 = csub(x0, rx2);
    float2 O0 = cadd(x1, x3), O2 = csub(x1, x3);
    float2 O1 = cadd(x1, rx3), O3 = csub(x1, rx3);
    float2 iO2 = (SIGN > 0) ? make_float2(-O2.y, O2.x) : make_float2(O2.y, -O2.x);
    float2 w1O1 = (SIGN > 0) ? make_float2(R2 * (O1.x - O1.y), R2 * (O1.y + O1.x))
                             : make_float2(R2 * (O1.x + O1.y), R2 * (O1.y - O1.x));
    float2 w3O3 = (SIGN > 0) ? make_float2(R2 * (-O3.x - O3.y), R2 * (O3.x - O3.y))
                             : make_float2(R2 * (O3.y - O3.x), R2 * (-O3.x - O3.y));
    x[0] = cadd(E0, O0);   x[4] = csub(E0, O0);
    x[1] = cadd(E1, w1O1); x[5] = csub(E1, w1O1);
    x[2] = cadd(E2, iO2);  x[6] = csub(E2, iO2);
    x[3] = cadd(E3, w3O3); x[7] = csub(E3, w3O3);
}

// twiddle by W4096^(base*i) from table (tab[j] = e^{-2pi i j/4096}); conj for inverse.
template<int SIGN>
__device__ __forceinline__ void twtab(float2 x[8], int base, const float2* __restrict__ tab) {
#pragma unroll
    for (int i = 1; i < 8; ++i) {
        float2 w = tab[base * i];
        x[i] = (SIGN < 0) ? cmul(x[i], w) : cmulc(x[i], w);
    }
}

// 4096-pt radix-8 Stockham FFT, t in [0,512), double-buffered LDS L0/L1.
template<int SIGN>
__device__ void fft4096(float2 x[8], int t, float2* L0, float2* L1,
                        const float2* __restrict__ tab) {
    dft8<SIGN>(x);
    twtab<SIGN>(x, t, tab);
#pragma unroll
    for (int i = 0; i < 8; ++i) L0[LB(8 * t + i)] = x[i];
    __syncthreads();
    {
        int q = t & 7, p = t >> 3;
#pragma unroll
        for (int i = 0; i < 8; ++i) x[i] = L0[LB(q + 8 * p + 512 * i)];
        dft8<SIGN>(x);
        twtab<SIGN>(x, 8 * p, tab);
#pragma unroll
        for (int i = 0; i < 8; ++i) L1[LB(q + 64 * p + 8 * i)] = x[i];
    }
    __syncthreads();
    {
        int q = t & 63, p = t >> 6;
#pragma unroll
        for (int i = 0; i < 8; ++i) x[i] = L1[LB(q + 64 * p + 512 * i)];
        dft8<SIGN>(x);
        twtab<SIGN>(x, 64 * p, tab);
#pragma unroll
        for (int i = 0; i < 8; ++i) L0[LB(q + 512 * p + 64 * i)] = x[i];
    }
    __syncthreads();
#pragma unroll
    for (int i = 0; i < 8; ++i) x[i] = L0[LB(t + 512 * i)];
    dft8<SIGN>(x);
}

// ka: 192 blocks x 512. Distributed 64-pt column FFT.
// t = tid>>6 (wave-uniform), c = tid&63 (lane-consecutive n2).
__global__ void __launch_bounds__(512) ka(const float* __restrict__ audio,
                                          const float* __restrict__ rir,
                                          float2* __restrict__ A1,
                                          float2* __restrict__ tab) {
    __shared__ float2 Lsh[64 * 64];       // [j][c], 32 KB, conflict-free
    const int bid = blockIdx.x;
    const int tid = threadIdx.x;
    const int t = tid >> 6;               // radix-8 slot (uniform per wave)
    const int c = tid & 63;               // column within block

    if (bid < 8)                          // fill W4096 table (read by kbf/kbi next)
        tab[bid * 512 + tid] = cexp_(-PI2_4096 * (float)(bid * 512 + tid));

    int seq = bid >> 6;
    int n2 = ((bid & 63) << 6) + c;
    float2 g[8];
    if (seq < 2) {
        const float* c0 = audio + (size_t)(2 * seq) * TLEN;
        const float* c1 = c0 + TLEN;
#pragma unroll
        for (int i = 0; i < 4; ++i) {
            int n = ((t + 8 * i) << 12) + n2;          // n1 = t+8i < 32 (nonzero half)
            g[i] = make_float2(c0[n], c1[n]);          // lanes: 64 consecutive floats
        }
    } else {
#pragma unroll
        for (int i = 0; i < 4; ++i) {
            int n = ((t + 8 * i) << 12) + n2;
            g[i] = make_float2(rir[TLEN - 1 - n], 0.f);
        }
    }
    dft8z<-1>(g);
#pragma unroll
    for (int i = 1; i < 8; ++i)
        g[i] = cmul(g[i], cexp_(-PI2_64 * (float)(t * i)));
#pragma unroll
    for (int i = 0; i < 8; ++i) Lsh[(t + 8 * i) * 64 + c] = g[i];   // phys x[t+8i]
    __syncthreads();
#pragma unroll
    for (int i = 0; i < 8; ++i) g[i] = Lsh[(8 * t + i) * 64 + c];   // phys x[8t+i]
    dft8<-1>(g);
    // W_N^{-n2*(8i+t)} = W_N^{-n2 t} * (W_N^{-8 n2})^i
    float2 w  = cexp_(-PI2_N * (float)(n2 * t));
    float2 st = cexp_(-PI2_32768 * (float)n2);
    float2* dst = A1 + ((size_t)seq << 18) + n2;
#pragma unroll
    for (int i = 0; i < 8; ++i) {
        dst[(size_t)(8 * i + t) << 12] = cmul(g[i], w);   // k1 = rev8(8t+i) = 8i+t
        w = cmul(w, st);                                  // lanes: 512B coalesced
    }
}

// kbf: 192 blocks x 512. One forward 4096-FFT per (seq,k1) row.
__global__ void __launch_bounds__(512) kbf(const float2* __restrict__ A1,
                                           float2* __restrict__ Spec,
                                           const float2* __restrict__ tab) {
    int t = threadIdx.x;
    __shared__ float2 L0[4608], L1[4608];
    const float2* src = A1 + ((size_t)blockIdx.x << 12);
    float2 x[8];
#pragma unroll
    for (int i = 0; i < 8; ++i) x[i] = src[t + 512 * i];
    fft4096<-1>(x, t, L0, L1, tab);
    float2* dst = Spec + ((size_t)blockIdx.x << 12) + t;
#pragma unroll
    for (int i = 0; i < 8; ++i) dst[512 * i] = x[i];
}

// kbi: 128 blocks x 512. z = bid>>6, k1 = bid&63. Pointwise + inverse FFT + twiddle.
__global__ void __launch_bounds__(512) kbi(const float2* __restrict__ Spec,
                                           float2* __restrict__ D,
                                           const float2* __restrict__ tab) {
    int k1 = blockIdx.x & 63;
    int t = threadIdx.x;
    __shared__ float2 L0[4608], L1[4608];

    const float2* sz = Spec + ((size_t)blockIdx.x << 12);          // row z*64+k1
    const float2* sr = Spec + ((size_t)(128 + k1) << 12);          // rir row
    float2 x[8], r8[8];
#pragma unroll
    for (int i = 0; i < 8; ++i) x[i] = sz[t + 512 * i];
#pragma unroll
    for (int i = 0; i < 8; ++i) r8[i] = sr[t + 512 * i];

    const float invN = 3.814697265625e-6f;  // 1/262144
#pragma unroll
    for (int i = 0; i < 8; ++i) {
        float2 y = cmul(x[i], r8[i]);
        x[i] = make_float2(y.x * invN, y.y * invN);
    }

    fft4096<1>(x, t, L0, L1, tab);

    // W_N^{+n2 k1}, n2 = t+512i: chain from W_N^{t k1}, step W_512^{k1}
    float2 w  = cexp_(PI2_N * (float)(t * k1));
    float2 st = cexp_(PI2_512 * (float)k1);
    float2* d = D + ((size_t)blockIdx.x << 12) + t;
#pragma unroll
    for (int i = 0; i < 8; ++i) {
        d[512 * i] = cmul(x[i], w);
        w = cmul(w, st);
    }
}

// kc: 128 blocks x 512. Distributed 64-pt inverse column FFT over k1 + unpack.
// Same wave-uniform t mapping as ka.
__global__ void __launch_bounds__(512) kc(const float2* __restrict__ D,
                                          float* __restrict__ out, int Lout,
                                          const float2* __restrict__ tab) {
    __shared__ float2 Lsh[64 * 64];       // [j][c]
    const int bid = blockIdx.x;
    const int tid = threadIdx.x;
    const int t = tid >> 6;
    const int c = tid & 63;
    int z = bid >> 6;
    int n2 = ((bid & 63) << 6) + c;

    const float2* src = D + ((size_t)z << 18) + n2;
    float2 g[8];
#pragma unroll
    for (int i = 0; i < 8; ++i)
        g[i] = src[(size_t)(8 * i + t) << 12];          // input[k1=8i+t]; 512B coalesced
    dft8<1>(g);
#pragma unroll
    for (int i = 1; i < 8; ++i)
        g[i] = cmulc(g[i], tab[64 * t * i]);            // W64^{+ti} = conj(tab[64 t i])
#pragma unroll
    for (int i = 0; i < 8; ++i) Lsh[(8 * t + i) * 64 + c] = g[i];   // phys x[8t+i]
    __syncthreads();
#pragma unroll
    for (int i = 0; i < 8; ++i) g[i] = Lsh[(t + 8 * i) * 64 + c];   // phys x[t+8i]
    dft8<1>(g);
    float* o0 = out + (size_t)(2 * z) * Lout;
    float* o1 = o0 + Lout;
#pragma unroll
    for (int i = 0; i < 8; ++i) {
        int n = ((t + 8 * i) << 12) + n2;               // n1 = t+8i natural
        if (n < Lout) { o0[n] = g[i].x; o1[n] = g[i].y; }
    }
}

extern "C" void kernel_launch(void* const* d_in, const int* in_sizes, int n_in,
                              void* d_out, int out_size, void* d_ws, size_t ws_size,
                              hipStream_t stream) {
    const float* audio = (const float*)d_in[0];   // (1, 4, T) f32
    const float* rir   = (const float*)d_in[1];   // (T,) f32
    float* out = (float*)d_out;                   // (1, 4, 2T-1) f32
    int Lout = out_size / 4;                      // 262143

    float2* A1   = (float2*)d_ws;                 // 3 * 2^18 complex
    float2* Spec = A1 + 3 * NTOT;                 // 3 * 2^18 complex
    float2* D    = Spec + 3 * NTOT;               // 2 * 2^18 complex
    float2* tab  = D + 2 * NTOT;                  // 4096 complex (32 KB)

    ka <<<192, 512, 0, stream>>>(audio, rir, A1, tab);
    kbf<<<192, 512, 0, stream>>>(A1, Spec, tab);
    kbi<<<128, 512, 0, stream>>>(Spec, D, tab);
    kc <<<128, 512, 0, stream>>>(D, out, Lout, tab);
}